// Round 4
// baseline (6195.868 us; speedup 1.0000x reference)
//
#include <hip/hip_runtime.h>
#include <hip/hip_fp16.h>

typedef _Float16 f16;
typedef _Float16 f16x8 __attribute__((ext_vector_type(8)));
typedef float f32x16 __attribute__((ext_vector_type(16)));

#define T_N 512
#define DSTEPS 48
#define TOTSTEPS 560
#define NWG 64

// ---- ws layout (bytes) ----
#define OFF_WHHE 0ull
#define SZ_WHH   (4096ull*1024*2)          // 8 MB
#define OFF_WHHD (OFF_WHHE + SZ_WHH)
#define OFF_WIHE (OFF_WHHD + SZ_WHH)
#define SZ_WIH   (4096ull*64*2)            // 512 KB
#define OFF_WIHD (OFF_WIHE + SZ_WIH)
#define OFF_WFC  (OFF_WIHD + SZ_WIH)
#define SZ_WFC   (64ull*1024*2)            // 128 KB
#define OFF_XP   (OFF_WFC + SZ_WFC)
#define SZ_XP    (512ull*4096*2)           // 4 MB
#define OFF_Y0   (OFF_XP + SZ_XP)
#define SZ_Y0    (4096ull*2)
#define OFF_BE   (OFF_Y0 + SZ_Y0)
#define OFF_BD   (OFF_BE + 4096ull*4)
#define OFF_FLG  (OFF_BD + 4096ull*4)
#define SZ_FLG   (561ull*256*4)            // flags[t][q(4)][w(64)], per producer-wave
#define OFF_H    ((OFF_FLG + SZ_FLG + 255ull) & ~255ull)
// h produced at step t: 65536 f16 at OFF_H + t*131072, layout [w_src(64)][b(64)][u(16)]

// ============================ prologue: pack to fp16 fragment-linear ============================
__global__ void prologue(const float* __restrict__ x, const float* __restrict__ y0,
    const float* __restrict__ wihE, const float* __restrict__ whhE,
    const float* __restrict__ bihE, const float* __restrict__ bhhE,
    const float* __restrict__ wihD, const float* __restrict__ whhD,
    const float* __restrict__ bihD, const float* __restrict__ bhhD,
    const float* __restrict__ wfc, char* __restrict__ ws)
{
  const long long gid = (long long)blockIdx.x * 256 + threadIdx.x;
  const long long gsz = (long long)gridDim.x * 256;
  f16* whhEp = (f16*)(ws + OFF_WHHE);
  f16* whhDp = (f16*)(ws + OFF_WHHD);
  f16* wihEp = (f16*)(ws + OFF_WIHE);
  f16* wihDp = (f16*)(ws + OFF_WIHD);
  f16* wfcp  = (f16*)(ws + OFF_WFC);
  f16* xp    = (f16*)(ws + OFF_XP);
  f16* y0p   = (f16*)(ws + OFF_Y0);
  float* be  = (float*)(ws + OFF_BE);
  float* bd  = (float*)(ws + OFF_BD);

  for (long long idx = gid; idx < 4194304ll; idx += gsz) {
    int j = (int)idx & 7, l = (int)(idx >> 3) & 63, kk = (int)(idx >> 9) & 31;
    int i = (int)(idx >> 14) & 1, ks = (int)(idx >> 15) & 1, w = (int)(idx >> 16);
    int nl = i * 32 + (l & 31);
    int grow = (nl >> 4) * 1024 + w * 16 + (nl & 15);
    int k = ks * 512 + kk * 16 + ((l >> 5) << 3) + j;
    whhEp[idx] = (f16)whhE[(long long)grow * 1024 + k];
    whhDp[idx] = (f16)whhD[(long long)grow * 1024 + k];
  }
  for (long long idx = gid; idx < 262144ll; idx += gsz) {
    int j = (int)idx & 7, l = (int)(idx >> 3) & 63, kx = (int)(idx >> 9) & 1;
    int i = (int)(idx >> 10) & 1, ks = (int)(idx >> 11) & 1, w = (int)(idx >> 12);
    int nl = i * 32 + (l & 31);
    int grow = (nl >> 4) * 1024 + w * 16 + (nl & 15);
    int k = (ks * 2 + kx) * 16 + ((l >> 5) << 3) + j;
    wihEp[idx] = (f16)wihE[grow * 64 + k];
    wihDp[idx] = (f16)wihD[grow * 64 + k];
  }
  for (long long idx = gid; idx < 65536ll; idx += gsz) {
    int j = (int)idx & 7, l = (int)(idx >> 3) & 63, kk = (int)(idx >> 9) & 31;
    int i = (int)(idx >> 14) & 1, ks = (int)(idx >> 15) & 1;
    int o = i * 32 + (l & 31);
    int k = ks * 512 + kk * 16 + ((l >> 5) << 3) + j;
    wfcp[idx] = (f16)wfc[o * 1024 + k];
  }
  for (long long idx = gid; idx < 2097152ll; idx += gsz) {
    int kw = (int)idx & 15, b = (int)(idx >> 4) & 63, kkx = (int)(idx >> 10) & 3, t = (int)(idx >> 12);
    xp[idx] = (f16)x[(long long)b * 32768 + t * 64 + kkx * 16 + kw];
  }
  for (long long idx = gid; idx < 4096ll; idx += gsz) {
    int kw = (int)idx & 15, b = (int)(idx >> 4) & 63, kkx = (int)(idx >> 10) & 3;
    y0p[idx] = (f16)y0[b * 64 + kkx * 16 + kw];
  }
  for (long long idx = gid; idx < 4096ll; idx += gsz) {
    be[idx] = bihE[idx] + bhhE[idx];
    bd[idx] = bihD[idx] + bhhD[idx];
  }
  // flags need no init: poison 0xAAAAAAAA != 1, producers store 1
}

// ============================ persistent LSTM kernel ============================
__device__ __forceinline__ float sigf(float x) { return 1.0f / (1.0f + __expf(-x)); }
__device__ __forceinline__ float tanhfast(float x) {
  x = fminf(fmaxf(x, -15.f), 15.f);
  float e = __expf(2.0f * x);
  return (e - 1.0f) / (e + 1.0f);
}

#define MFMA(a,b,c) __builtin_amdgcn_mfma_f32_32x32x16_f16((a),(b),(c),0,0,0)

__launch_bounds__(256, 1)
__global__ void lstm_persist(char* __restrict__ ws, float* __restrict__ out,
                             const float* __restrict__ bfc)
{
  const int w    = blockIdx.x;      // owns hidden units [w*16, w*16+16)
  const int tid  = threadIdx.x;
  const int lane = tid & 63;
  const int wave = tid >> 6;
  const int wm   = wave & 1;        // M-half (batch 0..31 / 32..63)
  const int ks   = wave >> 1;       // K-half (h units 0..511 / 512..1023)

  const f16* whhEp = (const f16*)(ws + OFF_WHHE) + (size_t)w * 65536;
  const f16* whhDp = (const f16*)(ws + OFF_WHHD) + (size_t)w * 65536;
  const f16* wihEp = (const f16*)(ws + OFF_WIHE) + (size_t)w * 4096;
  const f16* wihDp = (const f16*)(ws + OFF_WIHD) + (size_t)w * 4096;
  const f16* wfcp  = (const f16*)(ws + OFF_WFC);
  const f16* xp    = (const f16*)(ws + OFF_XP);
  const f16* y0p   = (const f16*)(ws + OFF_Y0);
  const float* be  = (const float*)(ws + OFF_BE);
  const float* bd  = (const float*)(ws + OFF_BD);
  unsigned* flags  = (unsigned*)(ws + OFF_FLG);
  f16* hb          = (f16*)(ws + OFF_H);

  __shared__ float lds_g[2][64][66];   // [ks][gate-row n][batch m]
  __shared__ float bias_s[2][64];

  if (tid < 64) {
    int g4 = tid >> 4, u = tid & 15;
    bias_s[0][tid] = be[g4 * 1024 + w * 16 + u];
    bias_s[1][tid] = bd[g4 * 1024 + w * 16 + u];
  }

  // A-frag offset inside a [64b][16k] K-block: row=wm*32+(lane&31), khalf=(lane>>5)
  const int aoff = (wm * 32 + (lane & 31)) * 16 + (lane >> 5) * 8;
  const int boff = lane * 8;          // lane-linear packed B
  const int bsel = tid >> 2;          // batch this thread updates (cell phase)
  const int u0   = (tid & 3) * 4;     // first of 4 owned unit-locals
  const int n0   = lane & 31;         // this lane's gate-row within its 32-tile

  // Direct per-wave poll set: wave (wm,ks)'s af reads h[b in 32wm..+32) from WGs [32ks..+32),
  // produced by waves q in {2wm,2wm+1} of those WGs -> exactly 1 flag per lane.
  // (own-WG LDS WAR is NOT covered by this set; barrier A below handles it.)
  const unsigned* fpoll = flags + (2 * wm + (lane >> 5)) * 64 + 32 * ks + (lane & 31);

  // Whh B-fragments: live in the AGPR half of the unified file (256 VGPR + 256 AGPR)
  f16x8 bf0[32], bf1[32];
#pragma unroll
  for (int kk = 0; kk < 32; ++kk) {
    bf0[kk] = *(const f16x8*)(whhEp + (size_t)ks * 32768 + kk * 512 + boff);
    bf1[kk] = *(const f16x8*)(whhEp + (size_t)ks * 32768 + 16384 + kk * 512 + boff);
  }

  float c0 = 0.f, c1 = 0.f, c2 = 0.f, c3 = 0.f;
  __syncthreads();

#pragma unroll 1
  for (int t = 0; t < TOTSTEPS; ++t) {
    const bool enc = (t < T_N);

    if (t == T_N) {   // decoder weight swap (register/stream only)
#pragma unroll
      for (int kk = 0; kk < 32; ++kk) {
        bf0[kk] = *(const f16x8*)(whhDp + (size_t)ks * 32768 + kk * 512 + boff);
        bf1[kk] = *(const f16x8*)(whhDp + (size_t)ks * 32768 + 16384 + kk * 512 + boff);
      }
    }

    // x-projection operands + MFMAs (independent of h -> fully before the wait)
    const f16* xblk = enc ? (xp + (size_t)t * 4096) : y0p;
    const f16* wihp = enc ? wihEp : wihDp;
    f16x8 xa0 = *(const f16x8*)(xblk + (ks * 2 + 0) * 1024 + aoff);
    f16x8 xa1 = *(const f16x8*)(xblk + (ks * 2 + 1) * 1024 + aoff);
    f16x8 wf0 = *(const f16x8*)(wihp + ((ks * 2 + 0) * 2 + 0) * 512 + boff);
    f16x8 wf1 = *(const f16x8*)(wihp + ((ks * 2 + 0) * 2 + 1) * 512 + boff);
    f16x8 wf2 = *(const f16x8*)(wihp + ((ks * 2 + 1) * 2 + 0) * 512 + boff);
    f16x8 wf3 = *(const f16x8*)(wihp + ((ks * 2 + 1) * 2 + 1) * 512 + boff);

    f32x16 acc0, acc1;
#pragma unroll
    for (int i = 0; i < 16; ++i) { acc0[i] = 0.f; acc1[i] = 0.f; }
    acc0 = MFMA(xa0, wf0, acc0); acc0 = MFMA(xa1, wf1, acc0);
    acc1 = MFMA(xa0, wf2, acc1); acc1 = MFMA(xa1, wf3, acc1);

    if (t > 0) {
      // direct wave-local spin: exactly the 64 flags this wave's af loads depend on
      const unsigned* fp = fpoll + (size_t)t * 256;
      unsigned v;
      do {
        v = __hip_atomic_load(fp, __ATOMIC_RELAXED, __HIP_MEMORY_SCOPE_AGENT);
        if (__all(v == 1u)) break;
        __builtin_amdgcn_s_sleep(1);
      } while (1);
      asm volatile("" ::: "memory");   // keep af loads below the gate

      // burst-load this wave's A quarter of h(t-1): 32 x 16B, all in flight
      const f16* hblk = hb + (size_t)(t - 1) * 65536;
      f16x8 af[32];
#pragma unroll
      for (int kk = 0; kk < 32; ++kk)
        af[kk] = *(const f16x8*)(hblk + (size_t)(ks * 32 + kk) * 1024 + aoff);

#pragma unroll
      for (int kk = 0; kk < 32; ++kk) {
        acc0 = MFMA(af[kk], bf0[kk], acc0);
        acc1 = MFMA(af[kk], bf1[kk], acc1);
      }
    }

    // bias folded into the ks=0 partial (once per (row,batch))
    if (ks == 0) {
      const float* bs = enc ? bias_s[0] : bias_s[1];
      float b0 = bs[n0], b1 = bs[32 + n0];
#pragma unroll
      for (int i = 0; i < 16; ++i) { acc0[i] += b0; acc1[i] += b1; }
    }

    // Barrier A (WAR): siblings arriving here are past their poll(t), hence past their
    // step-(t-1) cell reads of lds_g -> safe to overwrite.
    __syncthreads();

    // K-split partials to LDS
    {
      const int mb = wm * 32 + ((lane >> 5) << 2);
#pragma unroll
      for (int r = 0; r < 16; ++r) {
        const int m = mb + (r & 3) + ((r >> 2) << 3);
        lds_g[ks][n0][m]      = acc0[r];
        lds_g[ks][32 + n0][m] = acc1[r];
      }
    }
    __syncthreads();   // Barrier B (RAW): all partials landed

    // cell update: thread -> (batch bsel, unit-locals u0..u0+3); c in fp32 regs
    union { unsigned long long u64; f16 h4[4]; } hu;
    float cc[4] = {c0, c1, c2, c3};
#pragma unroll
    for (int j = 0; j < 4; ++j) {
      const int u = u0 + j;
      float ig = lds_g[0][u][bsel]      + lds_g[1][u][bsel];
      float fg = lds_g[0][16 + u][bsel] + lds_g[1][16 + u][bsel];
      float gg = lds_g[0][32 + u][bsel] + lds_g[1][32 + u][bsel];
      float og = lds_g[0][48 + u][bsel] + lds_g[1][48 + u][bsel];
      float cn = sigf(fg) * cc[j] + sigf(ig) * tanhfast(gg);
      cc[j] = cn;
      hu.h4[j] = (f16)(sigf(og) * tanhfast(cn));
    }
    c0 = cc[0]; c1 = cc[1]; c2 = cc[2]; c3 = cc[3];

    // write-through h slice: thread -> bytes [tid*8, tid*8+8); wave covers batches [wave*16,+16)
    {
      f16* dst = hb + (size_t)t * 65536 + (size_t)w * 1024 + bsel * 16 + u0;
      unsigned long long addr = (unsigned long long)(size_t)dst;
      asm volatile("global_store_dwordx2 %0, %1, off sc0 sc1" : : "v"(addr), "v"(hu.u64) : "memory");
    }
    // wave-local drain, then this wave's own flag — no workgroup barrier on the signal path
    asm volatile("s_waitcnt vmcnt(0)" ::: "memory");
    if (lane == 0) {
      unsigned* fa = flags + (size_t)(t + 1) * 256 + wave * 64 + w;
      unsigned long long addr = (unsigned long long)(size_t)fa;
      unsigned one = 1u;
      asm volatile("global_store_dword %0, %1, off sc0 sc1" : : "v"(addr), "v"(one) : "memory");
    }
  }

  // ---- FC epilogue: WG w<48 computes out[:, w*64..+64) from h of step 512+w ----
  if (w < DSTEPS) {
    __syncthreads();   // all sibling waves out of the main loop (lds_g WAR airtight)
    const int s = T_N + 1 + w;   // flag index of h produced at step 512+w
#pragma unroll
    for (int kk = 0; kk < 32; ++kk) {
      bf0[kk] = *(const f16x8*)(wfcp + (size_t)ks * 32768 + kk * 512 + boff);
      bf1[kk] = *(const f16x8*)(wfcp + (size_t)ks * 32768 + 16384 + kk * 512 + boff);
    }
    // direct poll at index s (same dependency pattern as the main loop)
    {
      const unsigned* fp = fpoll + (size_t)s * 256;
      unsigned v;
      do {
        v = __hip_atomic_load(fp, __ATOMIC_RELAXED, __HIP_MEMORY_SCOPE_AGENT);
        if (__all(v == 1u)) break;
        __builtin_amdgcn_s_sleep(1);
      } while (1);
      asm volatile("" ::: "memory");
    }

    const f16* hblk = hb + (size_t)(s - 1) * 65536;
    f16x8 af[32];
#pragma unroll
    for (int kk = 0; kk < 32; ++kk)
      af[kk] = *(const f16x8*)(hblk + (size_t)(ks * 32 + kk) * 1024 + aoff);

    f32x16 acc0, acc1;
#pragma unroll
    for (int i = 0; i < 16; ++i) { acc0[i] = 0.f; acc1[i] = 0.f; }
#pragma unroll
    for (int kk = 0; kk < 32; ++kk) {
      acc0 = MFMA(af[kk], bf0[kk], acc0);
      acc1 = MFMA(af[kk], bf1[kk], acc1);
    }
    {
      const int mb = wm * 32 + ((lane >> 5) << 2);
#pragma unroll
      for (int r = 0; r < 16; ++r) {
        const int m = mb + (r & 3) + ((r >> 2) << 3);
        lds_g[ks][n0][m]      = acc0[r];
        lds_g[ks][32 + n0][m] = acc1[r];
      }
    }
    __syncthreads();
    // thread -> batch bsel, features f0..f0+15 (ALL 64 features covered)
    const int f0 = (tid & 3) * 16;
    float* op = out + (size_t)bsel * 3072 + w * 64 + f0;
#pragma unroll
    for (int c4 = 0; c4 < 4; ++c4) {
      float v4[4];
#pragma unroll
      for (int j = 0; j < 4; ++j) {
        const int f = f0 + c4 * 4 + j;
        v4[j] = lds_g[0][f][bsel] + lds_g[1][f][bsel] + bfc[f];
      }
      *(float4*)(op + c4 * 4) = make_float4(v4[0], v4[1], v4[2], v4[3]);
    }
  }
}

// ============================ launch ============================
extern "C" void kernel_launch(void* const* d_in, const int* in_sizes, int n_in,
                              void* d_out, int out_size, void* d_ws, size_t ws_size,
                              hipStream_t stream) {
  const float* x    = (const float*)d_in[0];
  const float* y0   = (const float*)d_in[1];
  const float* wihE = (const float*)d_in[2];
  const float* whhE = (const float*)d_in[3];
  const float* bihE = (const float*)d_in[4];
  const float* bhhE = (const float*)d_in[5];
  const float* wihD = (const float*)d_in[6];
  const float* whhD = (const float*)d_in[7];
  const float* bihD = (const float*)d_in[8];
  const float* bhhD = (const float*)d_in[9];
  const float* wfc  = (const float*)d_in[10];
  const float* bfc  = (const float*)d_in[11];
  char* ws   = (char*)d_ws;
  float* out = (float*)d_out;

  prologue<<<256, 256, 0, stream>>>(x, y0, wihE, whhE, bihE, bhhE,
                                    wihD, whhD, bihD, bhhD, wfc, ws);
  lstm_persist<<<NWG, 256, 0, stream>>>(ws, out, bfc);
}

// Round 5
// 2776.132 us; speedup vs baseline: 2.2318x; 2.2318x over previous
//
#include <hip/hip_runtime.h>
#include <hip/hip_fp16.h>

typedef _Float16 f16;
typedef _Float16 f16x8 __attribute__((ext_vector_type(8)));
typedef float f32x16 __attribute__((ext_vector_type(16)));

#define T_N 512
#define DSTEPS 48
#define TOTSTEPS 560
#define NWG 64

// ---- ws layout (bytes) ----
#define OFF_WHHE 0ull
#define SZ_WHH   (4096ull*1024*2)          // 8 MB
#define OFF_WHHD (OFF_WHHE + SZ_WHH)
#define OFF_WIHE (OFF_WHHD + SZ_WHH)
#define SZ_WIH   (4096ull*64*2)            // 512 KB
#define OFF_WIHD (OFF_WIHE + SZ_WIH)
#define OFF_WFC  (OFF_WIHD + SZ_WIH)
#define SZ_WFC   (64ull*1024*2)            // 128 KB
#define OFF_XP   (OFF_WFC + SZ_WFC)
#define SZ_XP    (512ull*4096*2)           // 4 MB
#define OFF_Y0   (OFF_XP + SZ_XP)
#define SZ_Y0    (4096ull*2)
#define OFF_BE   (OFF_Y0 + SZ_Y0)
#define OFF_BD   (OFF_BE + 4096ull*4)
#define OFF_FLG  (OFF_BD + 4096ull*4)
#define SZ_FLG   (561ull*256*4)            // flags[t][q(4)][w(64)], per producer-wave
#define OFF_H    ((OFF_FLG + SZ_FLG + 255ull) & ~255ull)
// h produced at step t: 65536 f16 at OFF_H + t*131072, layout [w_src(64)][b(64)][u(16)]

// ============================ prologue: pack to fp16 fragment-linear ============================
__global__ void prologue(const float* __restrict__ x, const float* __restrict__ y0,
    const float* __restrict__ wihE, const float* __restrict__ whhE,
    const float* __restrict__ bihE, const float* __restrict__ bhhE,
    const float* __restrict__ wihD, const float* __restrict__ whhD,
    const float* __restrict__ bihD, const float* __restrict__ bhhD,
    const float* __restrict__ wfc, char* __restrict__ ws)
{
  const long long gid = (long long)blockIdx.x * 256 + threadIdx.x;
  const long long gsz = (long long)gridDim.x * 256;
  f16* whhEp = (f16*)(ws + OFF_WHHE);
  f16* whhDp = (f16*)(ws + OFF_WHHD);
  f16* wihEp = (f16*)(ws + OFF_WIHE);
  f16* wihDp = (f16*)(ws + OFF_WIHD);
  f16* wfcp  = (f16*)(ws + OFF_WFC);
  f16* xp    = (f16*)(ws + OFF_XP);
  f16* y0p   = (f16*)(ws + OFF_Y0);
  float* be  = (float*)(ws + OFF_BE);
  float* bd  = (float*)(ws + OFF_BD);

  for (long long idx = gid; idx < 4194304ll; idx += gsz) {
    int j = (int)idx & 7, l = (int)(idx >> 3) & 63, kk = (int)(idx >> 9) & 31;
    int i = (int)(idx >> 14) & 1, ks = (int)(idx >> 15) & 1, w = (int)(idx >> 16);
    int nl = i * 32 + (l & 31);
    int grow = (nl >> 4) * 1024 + w * 16 + (nl & 15);
    int k = ks * 512 + kk * 16 + ((l >> 5) << 3) + j;
    whhEp[idx] = (f16)whhE[(long long)grow * 1024 + k];
    whhDp[idx] = (f16)whhD[(long long)grow * 1024 + k];
  }
  for (long long idx = gid; idx < 262144ll; idx += gsz) {
    int j = (int)idx & 7, l = (int)(idx >> 3) & 63, kx = (int)(idx >> 9) & 1;
    int i = (int)(idx >> 10) & 1, ks = (int)(idx >> 11) & 1, w = (int)(idx >> 12);
    int nl = i * 32 + (l & 31);
    int grow = (nl >> 4) * 1024 + w * 16 + (nl & 15);
    int k = (ks * 2 + kx) * 16 + ((l >> 5) << 3) + j;
    wihEp[idx] = (f16)wihE[grow * 64 + k];
    wihDp[idx] = (f16)wihD[grow * 64 + k];
  }
  for (long long idx = gid; idx < 65536ll; idx += gsz) {
    int j = (int)idx & 7, l = (int)(idx >> 3) & 63, kk = (int)(idx >> 9) & 31;
    int i = (int)(idx >> 14) & 1, ks = (int)(idx >> 15) & 1;
    int o = i * 32 + (l & 31);
    int k = ks * 512 + kk * 16 + ((l >> 5) << 3) + j;
    wfcp[idx] = (f16)wfc[o * 1024 + k];
  }
  for (long long idx = gid; idx < 2097152ll; idx += gsz) {
    int kw = (int)idx & 15, b = (int)(idx >> 4) & 63, kkx = (int)(idx >> 10) & 3, t = (int)(idx >> 12);
    xp[idx] = (f16)x[(long long)b * 32768 + t * 64 + kkx * 16 + kw];
  }
  for (long long idx = gid; idx < 4096ll; idx += gsz) {
    int kw = (int)idx & 15, b = (int)(idx >> 4) & 63, kkx = (int)(idx >> 10) & 3;
    y0p[idx] = (f16)y0[b * 64 + kkx * 16 + kw];
  }
  for (long long idx = gid; idx < 4096ll; idx += gsz) {
    be[idx] = bihE[idx] + bhhE[idx];
    bd[idx] = bihD[idx] + bhhD[idx];
  }
  // flags need no init: poison 0xAAAAAAAA != 1, producers store 1
}

// ============================ persistent LSTM kernel ============================
__device__ __forceinline__ float sigf(float x) { return 1.0f / (1.0f + __expf(-x)); }
__device__ __forceinline__ float tanhfast(float x) {
  x = fminf(fmaxf(x, -15.f), 15.f);
  float e = __expf(2.0f * x);
  return (e - 1.0f) / (e + 1.0f);
}

#define MFMA(a,b,c) __builtin_amdgcn_mfma_f32_32x32x16_f16((a),(b),(c),0,0,0)

// NOTE (R4 lesson): the relay-poll + SINGLE-barrier step structure below is
// measured-fast (2829 us). Replacing it with direct per-wave polls + a second
// barrier between the MFMAs and the LDS writes regressed 2.2x. Do not touch
// the sync skeleton without an A/B.
__launch_bounds__(256, 1)
__global__ void lstm_persist(char* __restrict__ ws, float* __restrict__ out,
                             const float* __restrict__ bfc)
{
  const int w    = blockIdx.x;      // owns hidden units [w*16, w*16+16)
  const int tid  = threadIdx.x;
  const int lane = tid & 63;
  const int wave = tid >> 6;
  const int wm   = wave & 1;        // M-half (batch 0..31 / 32..63)
  const int ks   = wave >> 1;       // K-half (h units 0..511 / 512..1023)

  const f16* whhEp = (const f16*)(ws + OFF_WHHE) + (size_t)w * 65536;
  const f16* whhDp = (const f16*)(ws + OFF_WHHD) + (size_t)w * 65536;
  const f16* wihEp = (const f16*)(ws + OFF_WIHE) + (size_t)w * 4096;
  const f16* wihDp = (const f16*)(ws + OFF_WIHD) + (size_t)w * 4096;
  const f16* wfcp  = (const f16*)(ws + OFF_WFC);
  const f16* xp    = (const f16*)(ws + OFF_XP);
  const f16* y0p   = (const f16*)(ws + OFF_Y0);
  const float* be  = (const float*)(ws + OFF_BE);
  const float* bd  = (const float*)(ws + OFF_BD);
  unsigned* flags  = (unsigned*)(ws + OFF_FLG);
  f16* hb          = (f16*)(ws + OFF_H);

  __shared__ float lds_g[2][64][66];   // [ks][gate-row n][batch m]
  __shared__ float bias_s[2][64];
  __shared__ unsigned seen[2];         // seen[wm]: latest step whose needed flags were observed

  if (tid < 64) {
    int g4 = tid >> 4, u = tid & 15;
    bias_s[0][tid] = be[g4 * 1024 + w * 16 + u];
    bias_s[1][tid] = bd[g4 * 1024 + w * 16 + u];
  }
  if (tid < 2) seen[tid] = 0u;

  // A-frag offset inside a [64b][16k] K-block: row=wm*32+(lane&31), khalf=(lane>>5)
  const int aoff = (wm * 32 + (lane & 31)) * 16 + (lane >> 5) * 8;
  const int boff = lane * 8;          // lane-linear packed B
  const int bsel = tid >> 2;          // batch this thread updates (cell phase)
  const int u0   = (tid & 3) * 4;     // first of 4 owned unit-locals
  const int n0   = lane & 31;         // this lane's gate-row within its 32-tile

  // Whh B-fragments: live in the AGPR half of the unified file (VGPR_Count=256 + 256 AGPR)
  f16x8 bf0[32], bf1[32];
#pragma unroll
  for (int kk = 0; kk < 32; ++kk) {
    bf0[kk] = *(const f16x8*)(whhEp + (size_t)ks * 32768 + kk * 512 + boff);
    bf1[kk] = *(const f16x8*)(whhEp + (size_t)ks * 32768 + 16384 + kk * 512 + boff);
  }

  float c0 = 0.f, c1 = 0.f, c2 = 0.f, c3 = 0.f;
  __syncthreads();

#pragma unroll 1
  for (int t = 0; t < TOTSTEPS; ++t) {
    const bool enc = (t < T_N);

    if (t == T_N) {   // decoder weight swap (register/stream only)
#pragma unroll
      for (int kk = 0; kk < 32; ++kk) {
        bf0[kk] = *(const f16x8*)(whhDp + (size_t)ks * 32768 + kk * 512 + boff);
        bf1[kk] = *(const f16x8*)(whhDp + (size_t)ks * 32768 + 16384 + kk * 512 + boff);
      }
    }

    // x-projection operands (independent of h -> issue before the wait)
    const f16* xblk = enc ? (xp + (size_t)t * 4096) : y0p;
    const f16* wihp = enc ? wihEp : wihDp;
    f16x8 xa0 = *(const f16x8*)(xblk + (ks * 2 + 0) * 1024 + aoff);
    f16x8 xa1 = *(const f16x8*)(xblk + (ks * 2 + 1) * 1024 + aoff);
    f16x8 wf0 = *(const f16x8*)(wihp + ((ks * 2 + 0) * 2 + 0) * 512 + boff);
    f16x8 wf1 = *(const f16x8*)(wihp + ((ks * 2 + 0) * 2 + 1) * 512 + boff);
    f16x8 wf2 = *(const f16x8*)(wihp + ((ks * 2 + 1) * 2 + 0) * 512 + boff);
    f16x8 wf3 = *(const f16x8*)(wihp + ((ks * 2 + 1) * 2 + 1) * 512 + boff);

    // ---- split poll: wave0 watches set A (q=0,1 -> batches 0..31), wave1 set B (q=2,3).
    // Waves 2,3 spin on LDS seen[wm]. A wave's af loads (batches wm*32..+32) depend only on
    // its set; lds_g WAR is covered because set wm includes own-WG waves q{2wm,2wm+1} = exactly
    // the step-(t-1) readers of the columns wave(wm,ks) overwrites.
    if (t > 0) {
      if (wave < 2) {
        const unsigned* fp = flags + (size_t)t * 256 + wave * 128 + lane;
        int ok;
        do {
          unsigned v0 = __hip_atomic_load(fp,      __ATOMIC_RELAXED, __HIP_MEMORY_SCOPE_AGENT);
          unsigned v1 = __hip_atomic_load(fp + 64, __ATOMIC_RELAXED, __HIP_MEMORY_SCOPE_AGENT);
          ok = __all((v0 == 1u) & (v1 == 1u));
          if (!ok) __builtin_amdgcn_s_sleep(1);
        } while (!ok);
        __hip_atomic_store(&seen[wave], (unsigned)t, __ATOMIC_RELEASE, __HIP_MEMORY_SCOPE_WORKGROUP);
      } else {
        while (__hip_atomic_load(&seen[wm], __ATOMIC_ACQUIRE, __HIP_MEMORY_SCOPE_WORKGROUP) < (unsigned)t)
          __builtin_amdgcn_s_sleep(1);
      }
      asm volatile("" ::: "memory");   // keep af loads below the gate
    }

    // ---- burst-load this wave's A quarter of h(t-1): 32 x 16B, all in flight ----
    f16x8 af[32];
    if (t > 0) {
      const f16* hblk = hb + (size_t)(t - 1) * 65536;
#pragma unroll
      for (int kk = 0; kk < 32; ++kk)
        af[kk] = *(const f16x8*)(hblk + (size_t)(ks * 32 + kk) * 1024 + aoff);
    }

    f32x16 acc0, acc1;
#pragma unroll
    for (int i = 0; i < 16; ++i) { acc0[i] = 0.f; acc1[i] = 0.f; }
    acc0 = MFMA(xa0, wf0, acc0); acc0 = MFMA(xa1, wf1, acc0);
    acc1 = MFMA(xa0, wf2, acc1); acc1 = MFMA(xa1, wf3, acc1);

    if (t > 0) {
#pragma unroll
      for (int kk = 0; kk < 32; ++kk) {
        acc0 = MFMA(af[kk], bf0[kk], acc0);
        acc1 = MFMA(af[kk], bf1[kk], acc1);
      }
    }

    // branchless half-bias fold: each ks-half adds bias/2; the cell-phase sum restores it.
    // (removes 4 LDS bias reads + 4 adds from the serial cell path; halving is exact in fp32)
    {
      const float* bs = enc ? bias_s[0] : bias_s[1];
      const float b0h = 0.5f * bs[n0];
      const float b1h = 0.5f * bs[32 + n0];
#pragma unroll
      for (int i = 0; i < 16; ++i) { acc0[i] += b0h; acc1[i] += b1h; }
    }

    // K-split partials to LDS
    {
      const int mb = wm * 32 + ((lane >> 5) << 2);
#pragma unroll
      for (int r = 0; r < 16; ++r) {
        const int m = mb + (r & 3) + ((r >> 2) << 3);
        lds_g[ks][n0][m]      = acc0[r];
        lds_g[ks][32 + n0][m] = acc1[r];
      }
    }
    __syncthreads();

    // cell update: thread -> (batch bsel, unit-locals u0..u0+3); c in fp32 regs
    union { unsigned long long u64; f16 h4[4]; } hu;
    float cc[4] = {c0, c1, c2, c3};
#pragma unroll
    for (int j = 0; j < 4; ++j) {
      const int u = u0 + j;
      float ig = lds_g[0][u][bsel]      + lds_g[1][u][bsel];
      float fg = lds_g[0][16 + u][bsel] + lds_g[1][16 + u][bsel];
      float gg = lds_g[0][32 + u][bsel] + lds_g[1][32 + u][bsel];
      float og = lds_g[0][48 + u][bsel] + lds_g[1][48 + u][bsel];
      float cn = sigf(fg) * cc[j] + sigf(ig) * tanhfast(gg);
      cc[j] = cn;
      hu.h4[j] = (f16)(sigf(og) * tanhfast(cn));
    }
    c0 = cc[0]; c1 = cc[1]; c2 = cc[2]; c3 = cc[3];

    // write-through h slice: thread -> bytes [tid*8, tid*8+8); wave covers batches [wave*16,+16)
    {
      f16* dst = hb + (size_t)t * 65536 + (size_t)w * 1024 + bsel * 16 + u0;
      unsigned long long addr = (unsigned long long)(size_t)dst;
      asm volatile("global_store_dwordx2 %0, %1, off sc0 sc1" : : "v"(addr), "v"(hu.u64) : "memory");
    }
    // wave-local drain, then this wave's own flag — no workgroup barrier on the signal path
    asm volatile("s_waitcnt vmcnt(0)" ::: "memory");
    if (lane == 0) {
      unsigned* fa = flags + (size_t)(t + 1) * 256 + wave * 64 + w;
      unsigned long long addr = (unsigned long long)(size_t)fa;
      unsigned one = 1u;
      asm volatile("global_store_dword %0, %1, off sc0 sc1" : : "v"(addr), "v"(one) : "memory");
    }
    // (LDS WAR safety for t+1 comes from the split poll sets; see comment at the poll.)
  }

  // ---- FC epilogue: WG w<48 computes out[:, w*64..+64) from h of step 512+w ----
  if (w < DSTEPS) {
    __syncthreads();   // all sibling waves out of the main loop (lds_g WAR airtight)
    const int s = T_N + 1 + w;   // flag index of h produced at step 512+w
#pragma unroll
    for (int kk = 0; kk < 32; ++kk) {
      bf0[kk] = *(const f16x8*)(wfcp + (size_t)ks * 32768 + kk * 512 + boff);
      bf1[kk] = *(const f16x8*)(wfcp + (size_t)ks * 32768 + 16384 + kk * 512 + boff);
    }
    // split poll at index s; stale-high seen passes are safe by flag monotonicity
    // (seen=559 implies producers finished step 558 >= 512+w for all w<47; w=47 has s=560>559)
    if (wave < 2) {
      const unsigned* fp = flags + (size_t)s * 256 + wave * 128 + lane;
      int ok;
      do {
        unsigned v0 = __hip_atomic_load(fp,      __ATOMIC_RELAXED, __HIP_MEMORY_SCOPE_AGENT);
        unsigned v1 = __hip_atomic_load(fp + 64, __ATOMIC_RELAXED, __HIP_MEMORY_SCOPE_AGENT);
        ok = __all((v0 == 1u) & (v1 == 1u));
        if (!ok) __builtin_amdgcn_s_sleep(1);
      } while (!ok);
      __hip_atomic_store(&seen[wave], (unsigned)s, __ATOMIC_RELEASE, __HIP_MEMORY_SCOPE_WORKGROUP);
    } else {
      while (__hip_atomic_load(&seen[wm], __ATOMIC_ACQUIRE, __HIP_MEMORY_SCOPE_WORKGROUP) < (unsigned)s)
        __builtin_amdgcn_s_sleep(1);
    }
    asm volatile("" ::: "memory");

    const f16* hblk = hb + (size_t)(s - 1) * 65536;
    f16x8 af[32];
#pragma unroll
    for (int kk = 0; kk < 32; ++kk)
      af[kk] = *(const f16x8*)(hblk + (size_t)(ks * 32 + kk) * 1024 + aoff);

    f32x16 acc0, acc1;
#pragma unroll
    for (int i = 0; i < 16; ++i) { acc0[i] = 0.f; acc1[i] = 0.f; }
#pragma unroll
    for (int kk = 0; kk < 32; ++kk) {
      acc0 = MFMA(af[kk], bf0[kk], acc0);
      acc1 = MFMA(af[kk], bf1[kk], acc1);
    }
    {
      const int mb = wm * 32 + ((lane >> 5) << 2);
#pragma unroll
      for (int r = 0; r < 16; ++r) {
        const int m = mb + (r & 3) + ((r >> 2) << 3);
        lds_g[ks][n0][m]      = acc0[r];
        lds_g[ks][32 + n0][m] = acc1[r];
      }
    }
    __syncthreads();
    // thread -> batch bsel, features f0..f0+15 (ALL 64 features covered)
    const int f0 = (tid & 3) * 16;
    float* op = out + (size_t)bsel * 3072 + w * 64 + f0;
#pragma unroll
    for (int c4 = 0; c4 < 4; ++c4) {
      float v4[4];
#pragma unroll
      for (int j = 0; j < 4; ++j) {
        const int f = f0 + c4 * 4 + j;
        v4[j] = lds_g[0][f][bsel] + lds_g[1][f][bsel] + bfc[f];
      }
      *(float4*)(op + c4 * 4) = make_float4(v4[0], v4[1], v4[2], v4[3]);
    }
  }
}

// ============================ launch ============================
extern "C" void kernel_launch(void* const* d_in, const int* in_sizes, int n_in,
                              void* d_out, int out_size, void* d_ws, size_t ws_size,
                              hipStream_t stream) {
  const float* x    = (const float*)d_in[0];
  const float* y0   = (const float*)d_in[1];
  const float* wihE = (const float*)d_in[2];
  const float* whhE = (const float*)d_in[3];
  const float* bihE = (const float*)d_in[4];
  const float* bhhE = (const float*)d_in[5];
  const float* wihD = (const float*)d_in[6];
  const float* whhD = (const float*)d_in[7];
  const float* bihD = (const float*)d_in[8];
  const float* bhhD = (const float*)d_in[9];
  const float* wfc  = (const float*)d_in[10];
  const float* bfc  = (const float*)d_in[11];
  char* ws   = (char*)d_ws;
  float* out = (float*)d_out;

  prologue<<<256, 256, 0, stream>>>(x, y0, wihE, whhE, bihE, bhhE,
                                    wihD, whhD, bihD, bhhD, wfc, ws);
  lstm_persist<<<NWG, 256, 0, stream>>>(ws, out, bfc);
}